// Round 8
// baseline (6289.205 us; speedup 1.0000x reference)
//
#include <hip/hip_runtime.h>
#include <hip/hip_bf16.h>
#include <hip/hip_cooperative_groups.h>
#include <math.h>

namespace cg = cooperative_groups;

// ---------------------------------------------------------------------------
// MoE trading transformer forward, MI355X/gfx950.
// B=16 S=512 F_IN=46 D=256 H=8 (dh=32) L=6 E=8 DFF=1024 OUT=3.
// R8: whole 6-layer loop as ONE cooperative kernel (512 blocks x 256 thr,
// 2 blocks/CU co-resident: LDS 40KB, VGPR<=256 via __launch_bounds__(256,2)).
// Stages = block-strided task loops + grid.sync() between; removes ~48
// kernel-launch gaps. Host falls back to per-stage kernels (same device
// functions) if the cooperative launch is rejected.
// ---------------------------------------------------------------------------

typedef __bf16 bf16;
typedef __bf16 bf16x8 __attribute__((ext_vector_type(8)));
typedef __bf16 bf16x4 __attribute__((ext_vector_type(4)));
typedef float f32x4 __attribute__((ext_vector_type(4)));

#define NIN 41
#define GRID 512
#define SMEM_BYTES 40960

#define GLOAD_LDS(g, l)                                                    \
    __builtin_amdgcn_global_load_lds(                                      \
        (const __attribute__((address_space(1))) void*)(g),                \
        (__attribute__((address_space(3))) void*)(l), 16, 0, 0)

// swizzled LDS element index for (tile-local row r, col-chunk c) [8-bf16 chunks]
#define SWZ(r, c) (((r) * 8 + ((c) ^ ((r) & 7))) * 8)

struct InTab {
    const void* src[NIN];
    unsigned off[NIN];
    unsigned n[NIN];
};

struct MegaP {
    const bf16 *qkv_w, *qkv_b, *out_w, *out_b;
    const bf16 *ln1_s, *ln1_b, *ln2_s, *ln2_b;
    const bf16 *gate_w, *gate_b;
    const bf16 *e_w1, *e_b1, *e_w2, *e_b2;
    bf16 *h, *qkv, *aout, *projo, *hid0, *hid1, *moe0, *moe1, *vT;
    int* top_e;
    float* top_w;
    int* g_hist;
    int* ntiles;
    int* tileex;
    int* list;
    float* lw;
    float* auxs;
};

__device__ __forceinline__ float gelu_exact(float x) {
    return 0.5f * x * (1.0f + erff(x * 0.70710678118654752f));
}

// ---------------------------------------------------------------------------
// Stage: dense GEMM C = A @ W^T + bias (task-strided).
// VTOUT: cols gn>=512 go transposed to vT[b][h][d][s].
// ---------------------------------------------------------------------------
template <int BM, int BN, int WM, int WN, bool VTOUT>
__device__ void dev_gemm(char* smem, const bf16* __restrict__ A,
                         const bf16* __restrict__ W, const bf16* __restrict__ bias,
                         bf16* __restrict__ C, int MTILES, int NTILES, int K, int N,
                         bf16* __restrict__ vT) {
    constexpr int BK = 64;
    bf16* As = (bf16*)smem;
    bf16* Ws = (bf16*)(smem + BM * BK * 2);
    const int tid = threadIdx.x;
    const int wave = tid >> 6, lane = tid & 63;
    constexpr int WCOLS = BN / WN;
    const int wm0 = (wave / WCOLS) * WM, wn0 = (wave % WCOLS) * WN;
    constexpr int MT = WM / 16, NT = WN / 16;
    const int frow = lane & 15, fquad = lane >> 4;
    constexpr int AIT = BM / 32, BIT = BN / 32;

    for (int task = blockIdx.x; task < MTILES * NTILES; task += gridDim.x) {
        const int bm0 = (task % MTILES) * BM;
        const int bn0 = (task / MTILES) * BN;
        f32x4 acc[MT][NT] = {};
        const bf16* ag[AIT];
        const bf16* bg[BIT];
        unsigned al[AIT], bl[BIT];
#pragma unroll
        for (int i = 0; i < AIT; i++) {
            const int d = wave * (BM * 2) + i * 64 + lane;
            const int r = d >> 3, c = ((d & 7) ^ (r & 7)) * 8;
            ag[i] = A + (size_t)(bm0 + r) * K + c;
            al[i] = (unsigned)(wave * (BM * 2) + i * 64) * 8u;
        }
#pragma unroll
        for (int i = 0; i < BIT; i++) {
            const int d = wave * (BN * 2) + i * 64 + lane;
            const int r = d >> 3, c = ((d & 7) ^ (r & 7)) * 8;
            bg[i] = W + (size_t)(bn0 + r) * K + c;
            bl[i] = (unsigned)(wave * (BN * 2) + i * 64) * 8u;
        }
        for (int k0 = 0; k0 < K; k0 += BK) {
#pragma unroll
            for (int i = 0; i < AIT; i++) GLOAD_LDS(ag[i] + k0, &As[al[i]]);
#pragma unroll
            for (int i = 0; i < BIT; i++) GLOAD_LDS(bg[i] + k0, &Ws[bl[i]]);
            __syncthreads();
#pragma unroll
            for (int ks = 0; ks < BK / 32; ks++) {
                bf16x8 af[MT], bfr[NT];
#pragma unroll
                for (int mt = 0; mt < MT; mt++)
                    af[mt] = *(const bf16x8*)&As[SWZ(wm0 + mt * 16 + frow, ks * 4 + fquad)];
#pragma unroll
                for (int nt = 0; nt < NT; nt++)
                    bfr[nt] = *(const bf16x8*)&Ws[SWZ(wn0 + nt * 16 + frow, ks * 4 + fquad)];
#pragma unroll
                for (int mt = 0; mt < MT; mt++)
#pragma unroll
                    for (int nt = 0; nt < NT; nt++)
                        acc[mt][nt] = __builtin_amdgcn_mfma_f32_16x16x32_bf16(
                            af[mt], bfr[nt], acc[mt][nt], 0, 0, 0);
            }
            __syncthreads();
        }
#pragma unroll
        for (int mt = 0; mt < MT; mt++)
#pragma unroll
            for (int nt = 0; nt < NT; nt++) {
                const int gn = bn0 + wn0 + nt * 16 + frow;
                const float bv = (float)bias[gn];
#pragma unroll
                for (int r = 0; r < 4; r++) {
                    const int gm = bm0 + wm0 + mt * 16 + fquad * 4 + r;
                    const float v = acc[mt][nt][r] + bv;
                    if (VTOUT && gn >= 512) {
                        const int d = gn - 512;
                        const int bb = gm >> 9, s = gm & 511;
                        vT[((size_t)(bb * 8 + (d >> 5)) * 32 + (d & 31)) * 512 + s] = (bf16)v;
                    } else {
                        C[(size_t)gm * N + gn] = (bf16)v;
                    }
                }
            }
    }
}

// ---------------------------------------------------------------------------
// Stage: fused attention, 2048 tasks (16 qtiles x 128 bh).
// ---------------------------------------------------------------------------
__device__ void dev_attn(char* smem, const bf16* __restrict__ qkv,
                         const bf16* __restrict__ vT, bf16* __restrict__ aout) {
    bf16(*P)[520] = (bf16(*)[520])smem;
    float* wsum = (float*)(smem + 33280);  // [4][32]
    float* sinv = wsum + 128;              // [32]
    const int tid = threadIdx.x, wave = tid >> 6, lane = tid & 63;
    const int frow = lane & 15, fquad = lane >> 4;
    const float CST = 0.25505654f;  // (1/sqrt(32)) * log2(e)

    for (int task = blockIdx.x; task < 2048; task += gridDim.x) {
        const int s0 = (task & 15) * 32;
        const int bh = task >> 4;
        const int b = bh >> 3, hh = bh & 7;
        const size_t base = (size_t)b * 512;

        bf16x8 qf[2];
#pragma unroll
        for (int mt = 0; mt < 2; mt++)
            qf[mt] = *(const bf16x8*)&qkv[(base + s0 + mt * 16 + frow) * 768 + hh * 32 + fquad * 8];
        float rsum[2][4] = {};
#pragma unroll
        for (int k8 = 0; k8 < 8; k8++) {
            const int key0 = (wave * 8 + k8) * 16;
            bf16x8 kf = *(const bf16x8*)&qkv[(base + key0 + frow) * 768 + 256 + hh * 32 + fquad * 8];
#pragma unroll
            for (int mt = 0; mt < 2; mt++) {
                f32x4 c = {};
                c = __builtin_amdgcn_mfma_f32_16x16x32_bf16(qf[mt], kf, c, 0, 0, 0);
#pragma unroll
                for (int r = 0; r < 4; r++) {
                    const float e_ = __builtin_exp2f(fminf(c[r] * CST, 60.0f));
                    P[mt * 16 + fquad * 4 + r][key0 + frow] = (bf16)e_;
                    rsum[mt][r] += e_;
                }
            }
        }
#pragma unroll
        for (int mt = 0; mt < 2; mt++)
#pragma unroll
            for (int r = 0; r < 4; r++) {
#pragma unroll
                for (int m = 1; m < 16; m <<= 1)
                    rsum[mt][r] += __shfl_xor(rsum[mt][r], m, 64);
            }
        if (frow == 0) {
#pragma unroll
            for (int mt = 0; mt < 2; mt++)
#pragma unroll
                for (int r = 0; r < 4; r++)
                    wsum[wave * 32 + mt * 16 + fquad * 4 + r] = rsum[mt][r];
        }
        __syncthreads();
        if (tid < 32)
            sinv[tid] = 1.0f / (wsum[tid] + wsum[32 + tid] + wsum[64 + tid] + wsum[96 + tid]);

        {
            const int mt = wave >> 1, nt = wave & 1;
            const bf16* vrow = &vT[((size_t)(b * 8 + hh) * 32 + nt * 16 + frow) * 512];
            f32x4 o = {};
#pragma unroll
            for (int ks = 0; ks < 16; ks++) {
                bf16x8 pf = *(const bf16x8*)&P[mt * 16 + frow][ks * 32 + fquad * 8];
                bf16x8 vf = *(const bf16x8*)&vrow[ks * 32 + fquad * 8];
                o = __builtin_amdgcn_mfma_f32_16x16x32_bf16(pf, vf, o, 0, 0, 0);
            }
            __syncthreads();
            const int r0 = mt * 16 + fquad * 4;
#pragma unroll
            for (int r = 0; r < 4; r++)
                aout[(base + s0 + r0 + r) * 256 + hh * 32 + nt * 16 + frow] =
                    (bf16)(o[r] * sinv[r0 + r]);
        }
    }
}

// ---------------------------------------------------------------------------
// Stage: fused ln1 + gate. 128 tasks x 64 tokens.
// ---------------------------------------------------------------------------
__device__ void dev_gate(char* smem, const MegaP& p, int l) {
    bf16* hs = (bf16*)smem;                        // [64][264]
    bf16* gws = (bf16*)(smem + 33792);             // [8][264]
    float* lg = (float*)(smem + 33792 + 4224);     // [64][9]
    float* mxs = lg + 576;
    float* invs = mxs + 64;
    int* hist = (int*)(invs + 64);
    const int tid = threadIdx.x;

    for (int task = blockIdx.x; task < 128; task += gridDim.x) {
        {
            const int e = tid >> 5, k = (tid & 31) * 8;
            *(bf16x8*)&gws[e * 264 + k] = *(const bf16x8*)&p.gate_w[e * 256 + k];
        }
        if (tid < 16) hist[tid] = 0;

        // LN: 4 threads/token, 64 cols each
        const int tl = tid >> 2, part = tid & 3;
        const int tok = task * 64 + tl;
        const int c0 = part * 64;
        float s1 = 0.0f, s2 = 0.0f;
#pragma unroll
        for (int j = 0; j < 64; j += 8) {
            bf16x8 hv = *(const bf16x8*)&p.h[(size_t)tok * 256 + c0 + j];
            bf16x8 av = *(const bf16x8*)&p.projo[(size_t)tok * 256 + c0 + j];
            bf16x8 xw;
#pragma unroll
            for (int q = 0; q < 8; q++) {
                const float xq = (float)hv[q] + (float)av[q];
                xw[q] = (bf16)xq;
                s1 += xq;
                s2 += xq * xq;
            }
            *(bf16x8*)&hs[tl * 264 + c0 + j] = xw;
        }
        s1 += __shfl_xor(s1, 1, 64); s1 += __shfl_xor(s1, 2, 64);
        s2 += __shfl_xor(s2, 1, 64); s2 += __shfl_xor(s2, 2, 64);
        const float mean = s1 * (1.0f / 256.0f);
        const float var = fmaxf(s2 * (1.0f / 256.0f) - mean * mean, 0.0f);
        const float inv = rsqrtf(var + 1e-5f);
#pragma unroll
        for (int j = 0; j < 64; j += 8) {
            bf16x8 xw = *(const bf16x8*)&hs[tl * 264 + c0 + j];
            bf16x8 sv = *(const bf16x8*)&p.ln1_s[c0 + j];
            bf16x8 bv = *(const bf16x8*)&p.ln1_b[c0 + j];
            bf16x8 o;
#pragma unroll
            for (int q = 0; q < 8; q++)
                o[q] = (bf16)(((float)xw[q] - mean) * inv * (float)sv[q] + (float)bv[q]);
            *(bf16x8*)&hs[tl * 264 + c0 + j] = o;
            *(bf16x8*)&p.h[(size_t)tok * 256 + c0 + j] = o;
        }
        __syncthreads();

        // logits from LDS
        const int e = tid & 7;
#pragma unroll
        for (int pass = 0; pass < 2; pass++) {
            const int t2 = pass * 32 + (tid >> 3);
            float acc = 0.0f;
            for (int k = 0; k < 256; k += 8) {
                bf16x8 hv = *(const bf16x8*)&hs[t2 * 264 + k];
                bf16x8 wv = *(const bf16x8*)&gws[e * 264 + k];
#pragma unroll
                for (int q = 0; q < 8; q++) acc += (float)hv[q] * (float)wv[q];
            }
            lg[t2 * 9 + e] = acc + (float)p.gate_b[e];
        }
        __syncthreads();

        if (tid < 64) {
            const int t2 = task * 64 + tid;
            float lv[8];
#pragma unroll
            for (int j = 0; j < 8; j++) lv[j] = lg[tid * 9 + j];
            int i0 = 0;
#pragma unroll
            for (int j = 1; j < 8; j++)
                if (lv[j] > lv[i0]) i0 = j;
            int i1 = -1;
#pragma unroll
            for (int j = 0; j < 8; j++)
                if (j != i0 && (i1 < 0 || lv[j] > lv[i1])) i1 = j;
            const float p0 = 1.0f / (1.0f + expf(lv[i1] - lv[i0]));
            p.top_e[t2] = i0;         p.top_w[t2] = p0;
            p.top_e[8192 + t2] = i1;  p.top_w[8192 + t2] = 1.0f - p0;
            atomicAdd(&hist[i0], 1);
            atomicAdd(&hist[8 + i1], 1);
            const float mx = lv[i0];
            float se = 0.0f;
#pragma unroll
            for (int j = 0; j < 8; j++) se += expf(lv[j] - mx);
            mxs[tid] = mx;
            invs[tid] = 1.0f / se;
        }
        __syncthreads();
        if (tid < 8) {
            float s = 0.0f;
            for (int t = 0; t < 64; t++) s += expf(lg[t * 9 + tid] - mxs[t]) * invs[t];
            atomicAdd(&p.auxs[l * 8 + tid], s);
        }
        if (tid < 16) p.g_hist[task * 16 + tid] = hist[tid];
        __syncthreads();
    }
}

// ---------------------------------------------------------------------------
// Stage: route-build + scatter. 128 tasks (one per gate task).
// ---------------------------------------------------------------------------
__device__ void dev_scatter(char* smem, const MegaP& p) {
    int* gh = (int*)smem;        // [128][16]
    int* s_cnt = gh + 2048;
    int* s_pre = s_cnt + 16;
    int* s_off = s_pre + 16;
    int* pos = s_off + 16;
    const int tid = threadIdx.x;

    for (int task = blockIdx.x; task < 128; task += gridDim.x) {
        for (int i = tid; i < 2048; i += 256) gh[i] = p.g_hist[i];
        __syncthreads();
        if (tid < 16) {
            int run = 0, pre = 0;
            for (int b = 0; b < 128; b++) {
                if (b == task) pre = run;
                run += gh[b * 16 + tid];
            }
            s_cnt[tid] = run;
            s_pre[tid] = pre;
        }
        __syncthreads();
        if (tid < 2) {
            const int slot = tid;
            int o = 0;
            for (int e2 = 0; e2 < 8; e2++) {
                s_off[slot * 8 + e2] = o;
                const int nt = (s_cnt[slot * 8 + e2] + 127) >> 7;
                if (task == 0)
                    for (int t = 0; t < nt; t++) p.tileex[slot * 72 + (o >> 7) + t] = e2;
                o += nt << 7;
            }
            if (task == 0) p.ntiles[slot] = o >> 7;
        }
        __syncthreads();
        if (tid < 16) pos[tid] = s_off[tid] + s_pre[tid];
        __syncthreads();
        if (task == 0) {
            for (int idx = tid; idx < 2048; idx += 256) {
                const int seg = idx >> 7, i = idx & 127;
                const int slot = seg >> 3;
                const int start = s_off[seg] + s_cnt[seg];
                const int end = s_off[seg] + ((s_cnt[seg] + 127) & ~127);
                const int pp = start + i;
                if (pp < end) {
                    p.list[slot * 9216 + pp] = 8192;
                    p.lw[slot * 9216 + pp] = 0.0f;
                }
            }
        }
        if (tid < 64) {
            const int tok = task * 64 + tid;
#pragma unroll
            for (int slot = 0; slot < 2; slot++) {
                const int e = p.top_e[slot * 8192 + tok];
                const float w = p.top_w[slot * 8192 + tok];
                const int idx = atomicAdd(&pos[slot * 8 + e], 1);
                p.list[slot * 9216 + idx] = tok;
                p.lw[slot * 9216 + idx] = w;
            }
        }
        __syncthreads();
    }
}

// ---------------------------------------------------------------------------
// Stage: MoE w1, 1136 tasks (142 x 8).
// ---------------------------------------------------------------------------
__device__ void dev_w1(char* smem, const MegaP& p) {
    constexpr int BM = 128, BN = 128, BK = 64, WM = 64, WN = 64;
    constexpr int N = 1024, K = 256;
    bf16* As = (bf16*)smem;
    bf16* Ws = (bf16*)(smem + BM * BK * 2);
    const int tid = threadIdx.x;
    const int wave = tid >> 6, lane = tid & 63;
    const int wm0 = (wave >> 1) * WM, wn0 = (wave & 1) * WN;
    constexpr int MT = WM / 16, NT = WN / 16;
    const int frow = lane & 15, fquad = lane >> 4;

    for (int task = blockIdx.x; task < 1136; task += gridDim.x) {
        const int x = task % 142, ny = task / 142;
        const int slot = (x >= 71) ? 1 : 0;
        const int xi = x - slot * 71;
        if (xi >= p.ntiles[slot]) continue;
        const int* mylist = p.list + slot * 9216;
        const int e = p.tileex[slot * 72 + xi];
        const bf16* W = p.e_w1 + (size_t)e * N * K;
        const bf16* bias = p.e_b1 + e * N;
        bf16* C = slot ? p.hid1 : p.hid0;
        const int bm0 = xi * BM, bn0 = ny * BN;
        f32x4 acc[MT][NT] = {};
        const bf16* ag[4];
        const bf16* bg[4];
        unsigned al[4];
#pragma unroll
        for (int i = 0; i < 4; i++) {
            const int d = wave * 256 + i * 64 + lane;
            const int r = d >> 3, c = ((d & 7) ^ (r & 7)) * 8;
            ag[i] = p.h + (size_t)mylist[bm0 + r] * K + c;
            al[i] = (unsigned)(wave * 256 + i * 64) * 8u;
            bg[i] = W + (size_t)(bn0 + r) * K + c;
        }
        for (int k0 = 0; k0 < K; k0 += BK) {
#pragma unroll
            for (int i = 0; i < 4; i++) GLOAD_LDS(ag[i] + k0, &As[al[i]]);
#pragma unroll
            for (int i = 0; i < 4; i++) GLOAD_LDS(bg[i] + k0, &Ws[al[i]]);
            __syncthreads();
#pragma unroll
            for (int ks = 0; ks < 2; ks++) {
                bf16x8 af[MT], bfr[NT];
#pragma unroll
                for (int mt = 0; mt < MT; mt++)
                    af[mt] = *(const bf16x8*)&As[SWZ(wm0 + mt * 16 + frow, ks * 4 + fquad)];
#pragma unroll
                for (int nt = 0; nt < NT; nt++)
                    bfr[nt] = *(const bf16x8*)&Ws[SWZ(wn0 + nt * 16 + frow, ks * 4 + fquad)];
#pragma unroll
                for (int mt = 0; mt < MT; mt++)
#pragma unroll
                    for (int nt = 0; nt < NT; nt++)
                        acc[mt][nt] = __builtin_amdgcn_mfma_f32_16x16x32_bf16(
                            af[mt], bfr[nt], acc[mt][nt], 0, 0, 0);
            }
            __syncthreads();
        }
#pragma unroll
        for (int mt = 0; mt < MT; mt++)
#pragma unroll
            for (int nt = 0; nt < NT; nt++) {
                const int gn = bn0 + wn0 + nt * 16 + frow;
                const float bv = (float)bias[gn];
#pragma unroll
                for (int r = 0; r < 4; r++) {
                    const int gm = bm0 + wm0 + mt * 16 + fquad * 4 + r;
                    C[(size_t)gm * N + gn] = (bf16)gelu_exact(acc[mt][nt][r] + bv);
                }
            }
    }
}

// ---------------------------------------------------------------------------
// Stage: MoE w2, 568 tasks (142 x 4). Disjoint outputs moe0/moe1.
// ---------------------------------------------------------------------------
__device__ void dev_w2(char* smem, const MegaP& p) {
    constexpr int BM = 128, BN = 64, BK = 64, WM = 32;
    constexpr int N = 256, K = 1024;
    bf16* As = (bf16*)smem;
    bf16* Ws = (bf16*)(smem + BM * BK * 2);
    const int tid = threadIdx.x;
    const int wave = tid >> 6, lane = tid & 63;
    const int wm0 = wave * WM;
    constexpr int MT = WM / 16, NT = 4;
    const int frow = lane & 15, fquad = lane >> 4;

    for (int task = blockIdx.x; task < 568; task += gridDim.x) {
        const int x = task % 142, ny = task / 142;
        const int slot = (x >= 71) ? 1 : 0;
        const int xi = x - slot * 71;
        if (xi >= p.ntiles[slot]) continue;
        const bf16* A = slot ? p.hid1 : p.hid0;
        bf16* C = slot ? p.moe1 : p.moe0;
        const int* mylist = p.list + slot * 9216;
        const float* mylw = p.lw + slot * 9216;
        const int e = p.tileex[slot * 72 + xi];
        const bf16* W = p.e_w2 + (size_t)e * N * K;
        const bf16* bias = p.e_b2 + e * N;
        const int bm0 = xi * BM, bn0 = ny * BN;
        f32x4 acc[MT][NT] = {};
        const bf16* ag[4];
        const bf16* bg[2];
        unsigned al[4], bl[2];
#pragma unroll
        for (int i = 0; i < 4; i++) {
            const int d = wave * 256 + i * 64 + lane;
            const int r = d >> 3, c = ((d & 7) ^ (r & 7)) * 8;
            ag[i] = A + (size_t)(bm0 + r) * K + c;
            al[i] = (unsigned)(wave * 256 + i * 64) * 8u;
        }
#pragma unroll
        for (int i = 0; i < 2; i++) {
            const int d = wave * 128 + i * 64 + lane;
            const int r = d >> 3, c = ((d & 7) ^ (r & 7)) * 8;
            bg[i] = W + (size_t)(bn0 + r) * K + c;
            bl[i] = (unsigned)(wave * 128 + i * 64) * 8u;
        }
        for (int k0 = 0; k0 < K; k0 += BK) {
#pragma unroll
            for (int i = 0; i < 4; i++) GLOAD_LDS(ag[i] + k0, &As[al[i]]);
#pragma unroll
            for (int i = 0; i < 2; i++) GLOAD_LDS(bg[i] + k0, &Ws[bl[i]]);
            __syncthreads();
#pragma unroll
            for (int ks = 0; ks < 2; ks++) {
                bf16x8 af[MT], bfr[NT];
#pragma unroll
                for (int mt = 0; mt < MT; mt++)
                    af[mt] = *(const bf16x8*)&As[SWZ(wm0 + mt * 16 + frow, ks * 4 + fquad)];
#pragma unroll
                for (int nt = 0; nt < NT; nt++)
                    bfr[nt] = *(const bf16x8*)&Ws[SWZ(nt * 16 + frow, ks * 4 + fquad)];
#pragma unroll
                for (int mt = 0; mt < MT; mt++)
#pragma unroll
                    for (int nt = 0; nt < NT; nt++)
                        acc[mt][nt] = __builtin_amdgcn_mfma_f32_16x16x32_bf16(
                            af[mt], bfr[nt], acc[mt][nt], 0, 0, 0);
            }
            __syncthreads();
        }
#pragma unroll
        for (int mt = 0; mt < MT; mt++)
#pragma unroll
            for (int nt = 0; nt < NT; nt++) {
                const int gn = bn0 + nt * 16 + frow;
                const float bv = (float)bias[gn];
#pragma unroll
                for (int r = 0; r < 4; r++) {
                    const int gm = bm0 + wm0 + mt * 16 + fquad * 4 + r;
                    const float v = acc[mt][nt][r] + bv;
                    C[(size_t)mylist[gm] * 256 + gn] = (bf16)(mylw[gm] * v);
                }
            }
    }
}

// ---------------------------------------------------------------------------
// Stage: ln2. 512 tasks x 16 tokens (wave does 4 tokens).
// ---------------------------------------------------------------------------
__device__ void dev_ln2(const MegaP& p) {
    const int wave = threadIdx.x >> 6, lane = threadIdx.x & 63;
    const int c0 = lane * 4;
    for (int task = blockIdx.x; task < 512; task += gridDim.x) {
#pragma unroll
        for (int q = 0; q < 4; q++) {
            const int m = task * 16 + wave * 4 + q;
            bf16x4 hv = *(const bf16x4*)&p.h[(size_t)m * 256 + c0];
            bf16x4 av = *(const bf16x4*)&p.moe0[(size_t)m * 256 + c0];
            bf16x4 bv2 = *(const bf16x4*)&p.moe1[(size_t)m * 256 + c0];
            float x[4];
            float s1 = 0.0f, s2 = 0.0f;
#pragma unroll
            for (int j = 0; j < 4; j++) {
                x[j] = (float)hv[j] + (float)av[j] + (float)bv2[j];
                s1 += x[j];
                s2 += x[j] * x[j];
            }
#pragma unroll
            for (int msk = 1; msk < 64; msk <<= 1) {
                s1 += __shfl_xor(s1, msk, 64);
                s2 += __shfl_xor(s2, msk, 64);
            }
            const float mean = s1 * (1.0f / 256.0f);
            const float var = fmaxf(s2 * (1.0f / 256.0f) - mean * mean, 0.0f);
            const float inv = rsqrtf(var + 1e-5f);
            bf16x4 sv = *(const bf16x4*)&p.ln2_s[c0];
            bf16x4 bv = *(const bf16x4*)&p.ln2_b[c0];
            bf16x4 o;
#pragma unroll
            for (int j = 0; j < 4; j++)
                o[j] = (bf16)((x[j] - mean) * inv * (float)sv[j] + (float)bv[j]);
            *(bf16x4*)&p.h[(size_t)m * 256 + c0] = o;
        }
    }
}

// ---------------------------------------------------------------------------
// Cooperative mega-kernel: the whole 6-layer loop.
// ---------------------------------------------------------------------------
__global__ __launch_bounds__(256, 2) void mega_kernel(MegaP p) {
    __shared__ __attribute__((aligned(16))) char smem[SMEM_BYTES];
    cg::grid_group grid = cg::this_grid();
    for (int l = 0; l < 6; l++) {
        dev_gemm<64, 128, 32, 64, true>(smem, p.h, p.qkv_w, p.qkv_b, p.qkv, 128, 6, 256, 768, p.vT);
        __threadfence(); grid.sync();
        dev_attn(smem, p.qkv, p.vT, p.aout);
        __threadfence(); grid.sync();
        dev_gemm<64, 64, 32, 32, false>(smem, p.aout, p.out_w, p.out_b, p.projo, 128, 4, 256, 256, nullptr);
        __threadfence(); grid.sync();
        dev_gate(smem, p, l);
        __threadfence(); grid.sync();
        dev_scatter(smem, p);
        __threadfence(); grid.sync();
        dev_w1(smem, p);
        __threadfence(); grid.sync();
        dev_w2(smem, p);
        __threadfence(); grid.sync();
        dev_ln2(p);
        __threadfence(); grid.sync();
    }
}

// ---------------------------------------------------------------------------
// Fallback per-stage wrappers (same device functions, separate dispatches).
// ---------------------------------------------------------------------------
__global__ __launch_bounds__(256, 2) void k_qkv(const bf16* A, const bf16* W,
                                                const bf16* b, bf16* C, bf16* vT) {
    __shared__ __attribute__((aligned(16))) char smem[SMEM_BYTES];
    dev_gemm<64, 128, 32, 64, true>(smem, A, W, b, C, 128, 6, 256, 768, vT);
}
__global__ __launch_bounds__(256, 2) void k_outproj(const bf16* A, const bf16* W,
                                                    const bf16* b, bf16* C) {
    __shared__ __attribute__((aligned(16))) char smem[SMEM_BYTES];
    dev_gemm<64, 64, 32, 32, false>(smem, A, W, b, C, 128, 4, 256, 256, nullptr);
}
__global__ __launch_bounds__(256, 2) void k_attn(const bf16* qkv, const bf16* vT, bf16* aout) {
    __shared__ __attribute__((aligned(16))) char smem[SMEM_BYTES];
    dev_attn(smem, qkv, vT, aout);
}
__global__ __launch_bounds__(256, 2) void k_gate(MegaP p, int l) {
    __shared__ __attribute__((aligned(16))) char smem[SMEM_BYTES];
    dev_gate(smem, p, l);
}
__global__ __launch_bounds__(256, 2) void k_scatter(MegaP p) {
    __shared__ __attribute__((aligned(16))) char smem[SMEM_BYTES];
    dev_scatter(smem, p);
}
__global__ __launch_bounds__(256, 2) void k_w1(MegaP p) {
    __shared__ __attribute__((aligned(16))) char smem[SMEM_BYTES];
    dev_w1(smem, p);
}
__global__ __launch_bounds__(256, 2) void k_w2(MegaP p) {
    __shared__ __attribute__((aligned(16))) char smem[SMEM_BYTES];
    dev_w2(smem, p);
}
__global__ __launch_bounds__(256, 2) void k_ln2(MegaP p) { dev_ln2(p); }

// ---------------------------------------------------------------------------
// Pre/post kernels (unchanged from R7).
// ---------------------------------------------------------------------------
__global__ void sniff_kernel(const unsigned* __restrict__ xw, int* __restrict__ flag) {
    __shared__ int cnt;
    if (threadIdx.x == 0) cnt = 0;
    __syncthreads();
    const unsigned w = xw[threadIdx.x];
    const unsigned ex = (w >> 7) & 0xFFu;
    if (ex >= 107u && ex <= 133u) atomicAdd(&cnt, 1);
    __syncthreads();
    if (threadIdx.x == 0) *flag = (cnt >= 192) ? 1 : 0;
}

__global__ __launch_bounds__(256) void convert_kernel(
    InTab tab, bf16* __restrict__ dst_base, const int* __restrict__ flag) {
    const unsigned g0 = blockIdx.x * 1024u;
    int inp = 0;
#pragma unroll
    for (int i = 1; i < NIN; i++)
        if (g0 >= tab.off[i]) inp = i;
    const unsigned n = tab.n[inp];
    const unsigned i0 = g0 - tab.off[inp] + threadIdx.x * 4u;
    if (i0 >= n) return;
    const int isbf = *flag;
    bf16* dst = dst_base + tab.off[inp];
    const unsigned end = (i0 + 4u > n) ? n : i0 + 4u;
    if (isbf) {
        const unsigned short* s = (const unsigned short*)tab.src[inp];
        for (unsigned i = i0; i < end; i++) ((unsigned short*)dst)[i] = s[i];
    } else {
        const float* s = (const float*)tab.src[inp];
        for (unsigned i = i0; i < end; i++) dst[i] = (bf16)s[i];
    }
}

__global__ void out_convert_kernel(const float* __restrict__ st, void* __restrict__ out,
                                   const int* __restrict__ flag) {
    const int i = threadIdx.x;
    if (i >= 65) return;
    if (*flag) ((bf16*)out)[i] = (bf16)st[i];
    else       ((float*)out)[i] = st[i];
}

__global__ __launch_bounds__(256) void input_proj_kernel(
    const bf16* __restrict__ x, const bf16* __restrict__ w,
    const bf16* __restrict__ b, bf16* __restrict__ h) {
    const int m = blockIdx.x, t = threadIdx.x;
    __shared__ float xs[46];
    if (t < 46) xs[t] = (float)x[m * 46 + t];
    __syncthreads();
    float acc = (float)b[t];
#pragma unroll
    for (int k = 0; k < 46; k++) acc += xs[k] * (float)w[t * 46 + k];
    const int s = m & 511;
    const int i = t >> 1;
    const float dv = expf((float)(2 * i) * (-9.210340371976184f / 256.0f));
    const float ang = (float)s * dv;
    const float pe = (t & 1) ? cosf(ang) : sinf(ang);
    h[(size_t)m * 256 + t] = (bf16)(acc + pe);
}

__global__ __launch_bounds__(256) void pooled_attn_kernel(
    const bf16* __restrict__ qkv, const bf16* __restrict__ vT,
    bf16* __restrict__ pa) {
    const int wid = blockIdx.x * 4 + (threadIdx.x >> 6);
    const int lane = threadIdx.x & 63;
    const int b = wid >> 3, hh = wid & 7;
    const size_t base = (size_t)b * 512;
    const float scale = 0.17677669529663687f;
    float q[32];
#pragma unroll
    for (int d = 0; d < 32; d++) q[d] = (float)qkv[(base + 511) * 768 + hh * 32 + d];
    float sc[8];
    float mx = -1e30f;
#pragma unroll
    for (int j = 0; j < 8; j++) {
        const int key = lane + j * 64;
        const bf16* kr = &qkv[(base + key) * 768 + 256 + hh * 32];
        float s = 0.0f;
#pragma unroll
        for (int d = 0; d < 32; d++) s += q[d] * (float)kr[d];
        s *= scale;
        sc[j] = s;
        mx = fmaxf(mx, s);
    }
#pragma unroll
    for (int m = 1; m < 64; m <<= 1) mx = fmaxf(mx, __shfl_xor(mx, m, 64));
    float se = 0.0f;
#pragma unroll
    for (int j = 0; j < 8; j++) { sc[j] = expf(sc[j] - mx); se += sc[j]; }
#pragma unroll
    for (int m = 1; m < 64; m <<= 1) se += __shfl_xor(se, m, 64);
    float o[32] = {};
    const bf16* vb = &vT[(size_t)(b * 8 + hh) * 32 * 512];
#pragma unroll
    for (int d = 0; d < 32; d++) {
        const bf16* vr = vb + (size_t)d * 512;
#pragma unroll
        for (int j = 0; j < 8; j++)
            o[d] += sc[j] * (float)vr[lane + j * 64];
    }
#pragma unroll
    for (int d = 0; d < 32; d++) {
#pragma unroll
        for (int m = 1; m < 64; m <<= 1) o[d] += __shfl_xor(o[d], m, 64);
    }
    if (lane == 0) {
        const float inv = 1.0f / se;
        for (int d = 0; d < 32; d++) pa[b * 256 + hh * 32 + d] = (bf16)(o[d] * inv);
    }
}

__global__ __launch_bounds__(256) void pooled_proj_kernel(
    const bf16* __restrict__ pa, const bf16* __restrict__ w,
    const bf16* __restrict__ bias, bf16* __restrict__ pooled) {
    const int b = blockIdx.x, t = threadIdx.x;
    __shared__ float xs[256];
    xs[t] = (float)pa[b * 256 + t];
    __syncthreads();
    float acc = (float)bias[t];
    for (int k = 0; k < 256; k++) acc += xs[k] * (float)w[t * 256 + k];
    pooled[b * 256 + t] = (bf16)acc;
}

__global__ __launch_bounds__(256) void heads_kernel(
    const bf16* __restrict__ pooled,
    const bf16* __restrict__ aw1, const bf16* __restrict__ ab1,
    const bf16* __restrict__ aln1s, const bf16* __restrict__ aln1b,
    const bf16* __restrict__ aw2, const bf16* __restrict__ ab2,
    const bf16* __restrict__ aln2s, const bf16* __restrict__ aln2b,
    const bf16* __restrict__ aw3, const bf16* __restrict__ ab3,
    const bf16* __restrict__ pw1, const bf16* __restrict__ pb1,
    const bf16* __restrict__ pln1s, const bf16* __restrict__ pln1b,
    const bf16* __restrict__ pw2, const bf16* __restrict__ pb2,
    const bf16* __restrict__ pln2s, const bf16* __restrict__ pln2b,
    const bf16* __restrict__ pw3, const bf16* __restrict__ pb3,
    float* __restrict__ out) {
    const int b = blockIdx.x, t = threadIdx.x;
    __shared__ float pool[256], buf[256], buf2[256], r1[256], r2[256];
    pool[t] = (float)pooled[b * 256 + t];
    __syncthreads();

    auto block_ln = [&](float* v, int W, const bf16* ls, const bf16* lb) {
        const float val = (t < W) ? v[t] : 0.0f;
        r1[t] = val;
        r2[t] = val * val;
        __syncthreads();
        for (int off = 128; off > 0; off >>= 1) {
            if (t < off) { r1[t] += r1[t + off]; r2[t] += r2[t + off]; }
            __syncthreads();
        }
        const float mean = r1[0] / (float)W;
        const float var = fmaxf(r2[0] / (float)W - mean * mean, 0.0f);
        const float inv = rsqrtf(var + 1e-5f);
        __syncthreads();
        if (t < W) v[t] = (val - mean) * inv * (float)ls[t] + (float)lb[t];
        __syncthreads();
    };

    float a;
    if (t < 128) {
        a = (float)ab1[t];
        for (int k = 0; k < 256; k++) a += pool[k] * (float)aw1[t * 256 + k];
        buf[t] = gelu_exact(a);
    }
    __syncthreads();
    block_ln(buf, 128, aln1s, aln1b);
    if (t < 64) {
        a = (float)ab2[t];
        for (int k = 0; k < 128; k++) a += buf[k] * (float)aw2[t * 128 + k];
        buf2[t] = gelu_exact(a);
    }
    __syncthreads();
    block_ln(buf2, 64, aln2s, aln2b);
    if (t < 3) {
        a = (float)ab3[t];
        for (int k = 0; k < 64; k++) a += buf2[k] * (float)aw3[t * 64 + k];
        out[b * 3 + t] = a;
    }

    a = (float)pb1[t];
    for (int k = 0; k < 256; k++) a += pool[k] * (float)pw1[t * 256 + k];
    buf[t] = a;
    __syncthreads();
    block_ln(buf, 256, pln1s, pln1b);
    buf[t] = gelu_exact(buf[t]);
    __syncthreads();
    if (t < 128) {
        a = (float)pb2[t];
        for (int k = 0; k < 256; k++) a += buf[k] * (float)pw2[t * 256 + k];
        buf2[t] = a;
    }
    __syncthreads();
    block_ln(buf2, 128, pln2s, pln2b);
    if (t < 128) buf2[t] = gelu_exact(buf2[t]);
    __syncthreads();
    if (t == 0) {
        a = (float)pb3[0];
        for (int k = 0; k < 128; k++) a += buf2[k] * (float)pw3[k];
        out[48 + b] = a;
    }
}

__global__ void aux_kernel(const float* __restrict__ sums, float* __restrict__ out) {
    if (threadIdx.x == 0 && blockIdx.x == 0) {
        float tot = 0.0f;
        for (int l = 0; l < 6; l++)
            for (int e = 0; e < 8; e++) {
                const float mn = sums[l * 8 + e] * (1.0f / 8192.0f);
                tot += 8.0f * mn * mn;
            }
        out[64] = tot;
    }
}

// ---------------------------------------------------------------------------
extern "C" void kernel_launch(void* const* d_in, const int* in_sizes, int n_in,
                              void* d_out, int out_size, void* d_ws, size_t ws_size,
                              hipStream_t stream) {
    char* ws = (char*)d_ws;
    const size_t MB = 1024 * 1024;
    bf16*  h     = (bf16*)(ws);                        // 8193x256
    bf16*  moe0  = (bf16*)(ws + 8 * MB);
    bf16*  moe1  = (bf16*)(ws + 13 * MB);
    char*  ctrl  = ws + 20 * MB;
    float* auxs   = (float*)(ctrl + 0);                // 48 f32
    int*   flag   = (int*)(ctrl + 192);
    int*   ntiles = (int*)(ctrl + 256);                // [2]
    int*   tileex = (int*)(ctrl + 320);                // [2][72]
    float* ostage = (float*)(ctrl + 1024);             // 65 f32
    int*   g_hist = (int*)(ctrl + 2048);               // [128][16]
    int*   top_e  = (int*)(ctrl + 12288);              // [2][8192]
    float* top_w  = (float*)(ctrl + 77824);            // [2][8192]
    int*   list   = (int*)(ctrl + 143360);             // [2][9216]
    float* lw     = (float*)(ctrl + 217088);           // [2][9216]
    bf16*  qkv   = (bf16*)(ws + 24 * MB);              // 8192x768
    bf16*  aoutb = (bf16*)(ws + 40 * MB);              // 8192x256
    bf16*  projo = (bf16*)(ws + 48 * MB);              // 8192x256
    bf16*  hid0  = (bf16*)(ws + 56 * MB);              // 9216x1024
    bf16*  hid1  = (bf16*)(ws + 80 * MB);              // 9216x1024
    bf16*  vT    = (bf16*)(ws + 104 * MB);             // [16][8][32][512]
    bf16*  pattn  = (bf16*)(ws + 110 * MB);
    bf16*  pooled = (bf16*)(ws + 110 * MB + 8192);
    bf16*  cvbase = (bf16*)(ws + 112 * MB);            // ~10.6 MB

    InTab tab;
    unsigned off = 0;
    bf16* cv[NIN];
    for (int i = 0; i < NIN; i++) {
        tab.src[i] = d_in[i];
        tab.off[i] = off;
        tab.n[i] = (unsigned)in_sizes[i];
        cv[i] = cvbase + off;
        off += ((unsigned)in_sizes[i] + 1023u) & ~1023u;
    }
    const int cv_blocks = (int)(off >> 10);

    const bf16 *x = cv[0], *in_w = cv[1], *in_b = cv[2], *qkv_w = cv[3], *qkv_b = cv[4],
               *out_w = cv[5], *out_b = cv[6], *gate_w = cv[7], *gate_b = cv[8],
               *e_w1 = cv[9], *e_b1 = cv[10], *e_w2 = cv[11], *e_b2 = cv[12],
               *ln1_s = cv[13], *ln1_b = cv[14], *ln2_s = cv[15], *ln2_b = cv[16],
               *pqkv_w = cv[17], *pqkv_b = cv[18], *pout_w = cv[19], *pout_b = cv[20],
               *a_w1 = cv[21], *a_b1 = cv[22], *a_ln1s = cv[23], *a_ln1b = cv[24],
               *a_w2 = cv[25], *a_b2 = cv[26], *a_ln2s = cv[27], *a_ln2b = cv[28],
               *a_w3 = cv[29], *a_b3 = cv[30],
               *pr_w1 = cv[31], *pr_b1 = cv[32], *pr_ln1s = cv[33], *pr_ln1b = cv[34],
               *pr_w2 = cv[35], *pr_b2 = cv[36], *pr_ln2s = cv[37], *pr_ln2b = cv[38],
               *pr_w3 = cv[39], *pr_b3 = cv[40];

    sniff_kernel<<<1, 256, 0, stream>>>((const unsigned*)d_in[0], flag);
    convert_kernel<<<cv_blocks, 256, 0, stream>>>(tab, cvbase, flag);

    hipMemsetAsync(auxs, 0, 192, stream);
    input_proj_kernel<<<8192, 256, 0, stream>>>(x, in_w, in_b, h);

    MegaP mp;
    mp.qkv_w = qkv_w; mp.qkv_b = qkv_b; mp.out_w = out_w; mp.out_b = out_b;
    mp.ln1_s = ln1_s; mp.ln1_b = ln1_b; mp.ln2_s = ln2_s; mp.ln2_b = ln2_b;
    mp.gate_w = gate_w; mp.gate_b = gate_b;
    mp.e_w1 = e_w1; mp.e_b1 = e_b1; mp.e_w2 = e_w2; mp.e_b2 = e_b2;
    mp.h = h; mp.qkv = qkv; mp.aout = aoutb; mp.projo = projo;
    mp.hid0 = hid0; mp.hid1 = hid1; mp.moe0 = moe0; mp.moe1 = moe1; mp.vT = vT;
    mp.top_e = top_e; mp.top_w = top_w; mp.g_hist = g_hist;
    mp.ntiles = ntiles; mp.tileex = tileex; mp.list = list; mp.lw = lw;
    mp.auxs = auxs;

    void* kargs[] = { &mp };
    hipError_t cerr = hipLaunchCooperativeKernel((void*)mega_kernel, dim3(GRID),
                                                 dim3(256), kargs, 0, stream);
    if (cerr != hipSuccess) {
        (void)hipGetLastError();  // clear
        for (int l = 0; l < 6; l++) {
            k_qkv<<<GRID, 256, 0, stream>>>(h, qkv_w, qkv_b, qkv, vT);
            k_attn<<<GRID, 256, 0, stream>>>(qkv, vT, aoutb);
            k_outproj<<<GRID, 256, 0, stream>>>(aoutb, out_w, out_b, projo);
            k_gate<<<GRID, 256, 0, stream>>>(mp, l);
            k_scatter<<<GRID, 256, 0, stream>>>(mp);
            k_w1<<<GRID, 256, 0, stream>>>(mp);
            k_w2<<<GRID, 256, 0, stream>>>(mp);
            k_ln2<<<GRID, 256, 0, stream>>>(mp);
        }
    }

    // pooled attention tail
    k_qkv<<<GRID, 256, 0, stream>>>(h, pqkv_w, pqkv_b, qkv, vT);
    pooled_attn_kernel<<<32, 256, 0, stream>>>(qkv, vT, pattn);
    pooled_proj_kernel<<<16, 256, 0, stream>>>(pattn, pout_w, pout_b, pooled);

    heads_kernel<<<16, 256, 0, stream>>>(
        pooled,
        a_w1, a_b1, a_ln1s, a_ln1b, a_w2, a_b2, a_ln2s, a_ln2b, a_w3, a_b3,
        pr_w1, pr_b1, pr_ln1s, pr_ln1b, pr_w2, pr_b2, pr_ln2s, pr_ln2b, pr_w3, pr_b3,
        ostage);
    aux_kernel<<<1, 64, 0, stream>>>(auxs, ostage);
    out_convert_kernel<<<1, 128, 0, stream>>>(ostage, d_out, flag);
}

// Round 9
// 1089.395 us; speedup vs baseline: 5.7731x; 5.7731x over previous
//
#include <hip/hip_runtime.h>
#include <hip/hip_bf16.h>
#include <math.h>

// ---------------------------------------------------------------------------
// MoE trading transformer forward, MI355X/gfx950.
// B=16 S=512 F_IN=46 D=256 H=8 (dh=32) L=6 E=8 DFF=1024 OUT=3.
// R9: revert R8's cooperative mega-kernel (grid.sync measured ~110us each on
// 8 XCDs -> 6.3ms). Back to R7 per-stage graph-replayed dispatches, plus
// out-proj GEMM + ln1 + gate fused into one full-row kernel (BM=32,BN=256,
// grid 256): LN + gate logits in the GEMM epilogue, per-block hist/aux (no
// contended global atomics; aux summed in scatter). 7 dispatches/layer.
// ---------------------------------------------------------------------------

typedef __bf16 bf16;
typedef __bf16 bf16x8 __attribute__((ext_vector_type(8)));
typedef __bf16 bf16x4 __attribute__((ext_vector_type(4)));
typedef float f32x4 __attribute__((ext_vector_type(4)));

#define NIN 41

#define GLOAD_LDS(g, l)                                                    \
    __builtin_amdgcn_global_load_lds(                                      \
        (const __attribute__((address_space(1))) void*)(g),                \
        (__attribute__((address_space(3))) void*)(l), 16, 0, 0)

// swizzled LDS element index for (tile-local row r, col-chunk c) [8-bf16 chunks]
#define SWZ(r, c) (((r) * 8 + ((c) ^ ((r) & 7))) * 8)

struct InTab {
    const void* src[NIN];
    unsigned off[NIN];
    unsigned n[NIN];
};

__device__ __forceinline__ float gelu_exact(float x) {
    return 0.5f * x * (1.0f + erff(x * 0.70710678118654752f));
}

// ---------------------------------------------------------------------------
// Dtype sniffer (f32 vs bf16 storage). flag: 1=bf16, 0=f32.
// ---------------------------------------------------------------------------
__global__ void sniff_kernel(const unsigned* __restrict__ xw, int* __restrict__ flag) {
    __shared__ int cnt;
    if (threadIdx.x == 0) cnt = 0;
    __syncthreads();
    const unsigned w = xw[threadIdx.x];
    const unsigned ex = (w >> 7) & 0xFFu;
    if (ex >= 107u && ex <= 133u) atomicAdd(&cnt, 1);
    __syncthreads();
    if (threadIdx.x == 0) *flag = (cnt >= 192) ? 1 : 0;
}

__global__ __launch_bounds__(256) void convert_kernel(
    InTab tab, bf16* __restrict__ dst_base, const int* __restrict__ flag) {
    const unsigned g0 = blockIdx.x * 1024u;
    int inp = 0;
#pragma unroll
    for (int i = 1; i < NIN; i++)
        if (g0 >= tab.off[i]) inp = i;
    const unsigned n = tab.n[inp];
    const unsigned i0 = g0 - tab.off[inp] + threadIdx.x * 4u;
    if (i0 >= n) return;
    const int isbf = *flag;
    bf16* dst = dst_base + tab.off[inp];
    const unsigned end = (i0 + 4u > n) ? n : i0 + 4u;
    if (isbf) {
        const unsigned short* s = (const unsigned short*)tab.src[inp];
        for (unsigned i = i0; i < end; i++) ((unsigned short*)dst)[i] = s[i];
    } else {
        const float* s = (const float*)tab.src[inp];
        for (unsigned i = i0; i < end; i++) dst[i] = (bf16)s[i];
    }
}

__global__ void out_convert_kernel(const float* __restrict__ st, void* __restrict__ out,
                                   const int* __restrict__ flag) {
    const int i = threadIdx.x;
    if (i >= 65) return;
    if (*flag) ((bf16*)out)[i] = (bf16)st[i];
    else       ((float*)out)[i] = st[i];
}

// ---------------------------------------------------------------------------
// Dense MFMA GEMM (qkv projection), async-staged + swizzled.
// VTOUT: cols gn>=512 go transposed to vT[b][h][d][s].
// ---------------------------------------------------------------------------
template <int BM, int BN, int WM, int WN, bool VTOUT>
__global__ __launch_bounds__(256) void gemm_bt(
    const bf16* __restrict__ A, const bf16* __restrict__ W,
    const bf16* __restrict__ bias, bf16* __restrict__ C,
    int M, int N, int K, bf16* __restrict__ vT) {
    constexpr int BK = 64;
    __shared__ alignas(16) bf16 As[BM * BK];
    __shared__ alignas(16) bf16 Ws[BN * BK];
    const int bm0 = blockIdx.x * BM, bn0 = blockIdx.y * BN;
    const int tid = threadIdx.x;
    const int wave = tid >> 6, lane = tid & 63;
    constexpr int WCOLS = BN / WN;
    const int wm0 = (wave / WCOLS) * WM, wn0 = (wave % WCOLS) * WN;
    constexpr int MT = WM / 16, NT = WN / 16;
    f32x4 acc[MT][NT] = {};
    const int frow = lane & 15, fquad = lane >> 4;

    constexpr int AIT = BM / 32, BIT = BN / 32;
    const bf16* ag[AIT];
    const bf16* bg[BIT];
    unsigned al[AIT], bl[BIT];
#pragma unroll
    for (int i = 0; i < AIT; i++) {
        const int d = wave * (BM * 2) + i * 64 + lane;
        const int r = d >> 3, c = ((d & 7) ^ (r & 7)) * 8;
        ag[i] = A + (size_t)(bm0 + r) * K + c;
        al[i] = (unsigned)(wave * (BM * 2) + i * 64) * 8u;
    }
#pragma unroll
    for (int i = 0; i < BIT; i++) {
        const int d = wave * (BN * 2) + i * 64 + lane;
        const int r = d >> 3, c = ((d & 7) ^ (r & 7)) * 8;
        bg[i] = W + (size_t)(bn0 + r) * K + c;
        bl[i] = (unsigned)(wave * (BN * 2) + i * 64) * 8u;
    }

    for (int k0 = 0; k0 < K; k0 += BK) {
#pragma unroll
        for (int i = 0; i < AIT; i++) GLOAD_LDS(ag[i] + k0, &As[al[i]]);
#pragma unroll
        for (int i = 0; i < BIT; i++) GLOAD_LDS(bg[i] + k0, &Ws[bl[i]]);
        __syncthreads();
#pragma unroll
        for (int ks = 0; ks < BK / 32; ks++) {
            bf16x8 af[MT], bfr[NT];
#pragma unroll
            for (int mt = 0; mt < MT; mt++)
                af[mt] = *(const bf16x8*)&As[SWZ(wm0 + mt * 16 + frow, ks * 4 + fquad)];
#pragma unroll
            for (int nt = 0; nt < NT; nt++)
                bfr[nt] = *(const bf16x8*)&Ws[SWZ(wn0 + nt * 16 + frow, ks * 4 + fquad)];
#pragma unroll
            for (int mt = 0; mt < MT; mt++)
#pragma unroll
                for (int nt = 0; nt < NT; nt++)
                    acc[mt][nt] = __builtin_amdgcn_mfma_f32_16x16x32_bf16(
                        af[mt], bfr[nt], acc[mt][nt], 0, 0, 0);
        }
        __syncthreads();
    }

#pragma unroll
    for (int mt = 0; mt < MT; mt++)
#pragma unroll
        for (int nt = 0; nt < NT; nt++) {
            const int gn = bn0 + wn0 + nt * 16 + frow;
            const float bv = (float)bias[gn];
#pragma unroll
            for (int r = 0; r < 4; r++) {
                const int gm = bm0 + wm0 + mt * 16 + fquad * 4 + r;
                const float v = acc[mt][nt][r] + bv;
                if (VTOUT && gn >= 512) {
                    const int d = gn - 512;
                    const int bb = gm >> 9, s = gm & 511;
                    vT[((size_t)(bb * 8 + (d >> 5)) * 32 + (d & 31)) * 512 + s] = (bf16)v;
                } else {
                    C[(size_t)gm * N + gn] = (bf16)v;
                }
            }
        }
}

// ---------------------------------------------------------------------------
// R9 fused out-proj + ln1 + gate. grid 256 (32 token rows/block, full width).
// projo = aout @ out_w^T + out_b ; h = LN(h + projo)*s + b (written back);
// gate logits -> top-2 -> per-block hist + aux partials (no global atomics).
// ---------------------------------------------------------------------------
__global__ __launch_bounds__(256) void outproj_gate_kernel(
    const bf16* __restrict__ A,      // aout 8192x256
    const bf16* __restrict__ W,      // out_w 256x256
    const bf16* __restrict__ obias,  // out_b
    bf16* __restrict__ h,
    const bf16* __restrict__ lns, const bf16* __restrict__ lnb,
    const bf16* __restrict__ gw, const bf16* __restrict__ gb,
    int* __restrict__ top_e, float* __restrict__ top_w,
    int* __restrict__ g_hist, float* __restrict__ auxpart) {
    constexpr int BK = 64, K = 256;
    __shared__ alignas(16) char smem[40960];
    bf16* As = (bf16*)smem;               // 32x64
    bf16* Ws = (bf16*)(smem + 4096);      // 256x64
    bf16* gws = (bf16*)smem;              // reuse As after K-loop: [8][256]
    float* red = (float*)(smem + 36864);  // [32][2][2]
    float* lgred = (float*)(smem + 37376);// [32][2][8]
    int* hist = (int*)(smem + 39424);     // [16]
    float* auxl = (float*)(smem + 39488); // [8]
    const int tid = threadIdx.x;
    const int wave = tid >> 6, lane = tid & 63;
    const int frow = lane & 15, fquad = lane >> 4;
    const int wm0 = (wave >> 1) * 16, wn0 = (wave & 1) * 128;
    const int bm0 = blockIdx.x * 32;
    f32x4 acc[8] = {};

    const bf16* ag;
    unsigned al;
    {
        const int d = wave * 64 + lane;
        const int r = d >> 3, c = ((d & 7) ^ (r & 7)) * 8;
        ag = A + (size_t)(bm0 + r) * K + c;
        al = (unsigned)(wave * 64) * 8u;
    }
    const bf16* bg[8];
    unsigned bl[8];
#pragma unroll
    for (int i = 0; i < 8; i++) {
        const int d = wave * 512 + i * 64 + lane;
        const int r = d >> 3, c = ((d & 7) ^ (r & 7)) * 8;
        bg[i] = W + (size_t)r * K + c;
        bl[i] = (unsigned)(wave * 512 + i * 64) * 8u;
    }

    for (int k0 = 0; k0 < K; k0 += BK) {
        GLOAD_LDS(ag + k0, &As[al]);
#pragma unroll
        for (int i = 0; i < 8; i++) GLOAD_LDS(bg[i] + k0, &Ws[bl[i]]);
        __syncthreads();
#pragma unroll
        for (int ks = 0; ks < 2; ks++) {
            bf16x8 af = *(const bf16x8*)&As[SWZ(wm0 + frow, ks * 4 + fquad)];
#pragma unroll
            for (int nt = 0; nt < 8; nt++) {
                bf16x8 bfr = *(const bf16x8*)&Ws[SWZ(wn0 + nt * 16 + frow, ks * 4 + fquad)];
                acc[nt] = __builtin_amdgcn_mfma_f32_16x16x32_bf16(af, bfr, acc[nt], 0, 0, 0);
            }
        }
        __syncthreads();
    }

    // ---- epilogue: residual + LN + gate ----
    {   // stage gate weights into the dead As region; init hist/aux
        const int e = tid >> 5, k = (tid & 31) * 8;
        *(bf16x8*)&gws[e * 256 + k] = *(const bf16x8*)&gw[e * 256 + k];
    }
    if (tid < 16) hist[tid] = 0;
    if (tid < 8) auxl[tid] = 0.0f;

    float val[8][4];
    float s1[4] = {0.f, 0.f, 0.f, 0.f}, s2[4] = {0.f, 0.f, 0.f, 0.f};
#pragma unroll
    for (int nt = 0; nt < 8; nt++) {
        const int gn = wn0 + nt * 16 + frow;
        const float bv = (float)obias[gn];
#pragma unroll
        for (int r = 0; r < 4; r++) {
            const int gm = bm0 + wm0 + fquad * 4 + r;
            const float v = acc[nt][r] + bv + (float)h[(size_t)gm * 256 + gn];
            val[nt][r] = v;
            s1[r] += v;
            s2[r] += v * v;
        }
    }
#pragma unroll
    for (int r = 0; r < 4; r++) {
#pragma unroll
        for (int m = 1; m < 16; m <<= 1) {
            s1[r] += __shfl_xor(s1[r], m, 64);
            s2[r] += __shfl_xor(s2[r], m, 64);
        }
    }
    if (frow == 0) {
#pragma unroll
        for (int r = 0; r < 4; r++) {
            const int row = wm0 + fquad * 4 + r;
            red[(row * 2 + (wave & 1)) * 2 + 0] = s1[r];
            red[(row * 2 + (wave & 1)) * 2 + 1] = s2[r];
        }
    }
    __syncthreads();

    float lp[8][4];
#pragma unroll
    for (int e = 0; e < 8; e++)
#pragma unroll
        for (int r = 0; r < 4; r++) lp[e][r] = 0.0f;
#pragma unroll
    for (int r = 0; r < 4; r++) {
        const int row = wm0 + fquad * 4 + r;
        const float t1 = red[(row * 2 + 0) * 2 + 0] + red[(row * 2 + 1) * 2 + 0];
        const float t2 = red[(row * 2 + 0) * 2 + 1] + red[(row * 2 + 1) * 2 + 1];
        const float mean = t1 * (1.0f / 256.0f);
        const float var = fmaxf(t2 * (1.0f / 256.0f) - mean * mean, 0.0f);
        const float inv = rsqrtf(var + 1e-5f);
#pragma unroll
        for (int nt = 0; nt < 8; nt++) {
            const int gn = wn0 + nt * 16 + frow;
            const float hn = (val[nt][r] - mean) * inv * (float)lns[gn] + (float)lnb[gn];
            h[(size_t)(bm0 + row) * 256 + gn] = (bf16)hn;
            val[nt][r] = hn;
        }
    }
#pragma unroll
    for (int nt = 0; nt < 8; nt++) {
        const int gn = wn0 + nt * 16 + frow;
#pragma unroll
        for (int e = 0; e < 8; e++) {
            const float wv = (float)gws[e * 256 + gn];
#pragma unroll
            for (int r = 0; r < 4; r++) lp[e][r] += val[nt][r] * wv;
        }
    }
#pragma unroll
    for (int e = 0; e < 8; e++)
#pragma unroll
        for (int r = 0; r < 4; r++) {
#pragma unroll
            for (int m = 1; m < 16; m <<= 1)
                lp[e][r] += __shfl_xor(lp[e][r], m, 64);
        }
    if (frow == 0) {
#pragma unroll
        for (int r = 0; r < 4; r++) {
            const int row = wm0 + fquad * 4 + r;
#pragma unroll
            for (int e = 0; e < 8; e++)
                lgred[(row * 2 + (wave & 1)) * 8 + e] = lp[e][r];
        }
    }
    __syncthreads();

    if ((wave & 1) == 0 && frow == 0) {
#pragma unroll
        for (int r = 0; r < 4; r++) {
            const int row = wm0 + fquad * 4 + r;
            const int tok = bm0 + row;
            float l[8];
#pragma unroll
            for (int e = 0; e < 8; e++)
                l[e] = lgred[(row * 2 + 0) * 8 + e] + lgred[(row * 2 + 1) * 8 + e] + (float)gb[e];
            int i0 = 0;
#pragma unroll
            for (int j = 1; j < 8; j++)
                if (l[j] > l[i0]) i0 = j;
            int i1 = -1;
#pragma unroll
            for (int j = 0; j < 8; j++)
                if (j != i0 && (i1 < 0 || l[j] > l[i1])) i1 = j;
            const float p0 = 1.0f / (1.0f + expf(l[i1] - l[i0]));
            top_e[tok] = i0;         top_w[tok] = p0;
            top_e[8192 + tok] = i1;  top_w[8192 + tok] = 1.0f - p0;
            atomicAdd(&hist[i0], 1);
            atomicAdd(&hist[8 + i1], 1);
            const float mx = l[i0];
            float se = 0.0f, pe[8];
#pragma unroll
            for (int j = 0; j < 8; j++) { pe[j] = expf(l[j] - mx); se += pe[j]; }
            const float sinv = 1.0f / se;
#pragma unroll
            for (int j = 0; j < 8; j++) atomicAdd(&auxl[j], pe[j] * sinv);
        }
    }
    __syncthreads();
    if (tid < 16) g_hist[blockIdx.x * 16 + tid] = hist[tid];
    if (tid < 8) auxpart[blockIdx.x * 8 + tid] = auxl[tid];
}

// ---------------------------------------------------------------------------
// Route-build + scatter (256 gate-blocks x 32 tokens). grid 256.
// Block 0 also: ntiles/tile_ex, pad fill, aux sum (single writer, no atomics).
// ---------------------------------------------------------------------------
__global__ __launch_bounds__(256) void scatter_route_kernel(
    const int* __restrict__ g_hist, const float* __restrict__ auxpart,
    const int* __restrict__ top_e, const float* __restrict__ top_w,
    int* __restrict__ ntiles, int* __restrict__ tile_ex,
    int* __restrict__ list, float* __restrict__ lw, float* __restrict__ auxs) {
    __shared__ int gh[256 * 16];
    __shared__ int s_cnt[16], s_pre[16], s_off[16], pos[16];
    const int tid = threadIdx.x;
    for (int i = tid; i < 4096; i += 256) gh[i] = g_hist[i];
    __syncthreads();
    if (tid < 16) {
        int run = 0, pre = 0;
        for (int b = 0; b < 256; b++) {
            if (b == (int)blockIdx.x) pre = run;
            run += gh[b * 16 + tid];
        }
        s_cnt[tid] = run;
        s_pre[tid] = pre;
    }
    __syncthreads();
    if (tid < 2) {
        const int slot = tid;
        int o = 0;
        for (int e2 = 0; e2 < 8; e2++) {
            s_off[slot * 8 + e2] = o;
            const int nt = (s_cnt[slot * 8 + e2] + 127) >> 7;
            if (blockIdx.x == 0)
                for (int t = 0; t < nt; t++) tile_ex[slot * 72 + (o >> 7) + t] = e2;
            o += nt << 7;
        }
        if (blockIdx.x == 0) ntiles[slot] = o >> 7;
    }
    __syncthreads();
    if (tid < 16) pos[tid] = s_off[tid] + s_pre[tid];
    __syncthreads();
    if (blockIdx.x == 0) {
        for (int idx = tid; idx < 2048; idx += 256) {
            const int seg = idx >> 7, i = idx & 127;
            const int slot = seg >> 3;
            const int start = s_off[seg] + s_cnt[seg];
            const int end = s_off[seg] + ((s_cnt[seg] + 127) & ~127);
            const int p = start + i;
            if (p < end) {
                list[slot * 9216 + p] = 8192;
                lw[slot * 9216 + p] = 0.0f;
            }
        }
        if (tid < 8) {
            float s = 0.0f;
            for (int b = 0; b < 256; b++) s += auxpart[b * 8 + tid];
            auxs[tid] = s;
        }
    }
    if (tid < 32) {
        const int tok = blockIdx.x * 32 + tid;
#pragma unroll
        for (int slot = 0; slot < 2; slot++) {
            const int e = top_e[slot * 8192 + tok];
            const float w = top_w[slot * 8192 + tok];
            const int idx = atomicAdd(&pos[slot * 8 + e], 1);
            list[slot * 9216 + idx] = tok;
            lw[slot * 9216 + idx] = w;
        }
    }
}

// ---------------------------------------------------------------------------
// MoE w1 (both slots): hid{slot}[i] = GELU(h[list[i]] @ w1_e^T + b1_e)
// grid (142, 8).
// ---------------------------------------------------------------------------
__global__ __launch_bounds__(256) void gemm_moe_w1(
    const bf16* __restrict__ A, const bf16* __restrict__ Wb,
    const bf16* __restrict__ biasb, bf16* __restrict__ hid0,
    bf16* __restrict__ hid1, const int* __restrict__ list,
    const int* __restrict__ tile_ex, const int* __restrict__ ntiles) {
    constexpr int BM = 128, BN = 128, BK = 64, WM = 64, WN = 64;
    constexpr int N = 1024, K = 256;
    const int slot = (blockIdx.x >= 71) ? 1 : 0;
    const int xi = blockIdx.x - slot * 71;
    if (xi >= ntiles[slot]) return;
    __shared__ alignas(16) bf16 As[BM * BK];
    __shared__ alignas(16) bf16 Ws[BN * BK];
    const int* mylist = list + slot * 9216;
    const int e = tile_ex[slot * 72 + xi];
    const bf16* W = Wb + (size_t)e * N * K;
    const bf16* bias = biasb + e * N;
    bf16* C = slot ? hid1 : hid0;
    const int bm0 = xi * BM, bn0 = blockIdx.y * BN;
    const int tid = threadIdx.x;
    const int wave = tid >> 6, lane = tid & 63;
    const int wm0 = (wave >> 1) * WM, wn0 = (wave & 1) * WN;
    constexpr int MT = WM / 16, NT = WN / 16;
    f32x4 acc[MT][NT] = {};
    const int frow = lane & 15, fquad = lane >> 4;

    const bf16* ag[4];
    const bf16* bg[4];
    unsigned al[4];
#pragma unroll
    for (int i = 0; i < 4; i++) {
        const int d = wave * 256 + i * 64 + lane;
        const int r = d >> 3, c = ((d & 7) ^ (r & 7)) * 8;
        ag[i] = A + (size_t)mylist[bm0 + r] * K + c;
        al[i] = (unsigned)(wave * 256 + i * 64) * 8u;
        bg[i] = W + (size_t)(bn0 + r) * K + c;
    }

    for (int k0 = 0; k0 < K; k0 += BK) {
#pragma unroll
        for (int i = 0; i < 4; i++) GLOAD_LDS(ag[i] + k0, &As[al[i]]);
#pragma unroll
        for (int i = 0; i < 4; i++) GLOAD_LDS(bg[i] + k0, &Ws[al[i]]);
        __syncthreads();
#pragma unroll
        for (int ks = 0; ks < 2; ks++) {
            bf16x8 af[MT], bfr[NT];
#pragma unroll
            for (int mt = 0; mt < MT; mt++)
                af[mt] = *(const bf16x8*)&As[SWZ(wm0 + mt * 16 + frow, ks * 4 + fquad)];
#pragma unroll
            for (int nt = 0; nt < NT; nt++)
                bfr[nt] = *(const bf16x8*)&Ws[SWZ(wn0 + nt * 16 + frow, ks * 4 + fquad)];
#pragma unroll
            for (int mt = 0; mt < MT; mt++)
#pragma unroll
                for (int nt = 0; nt < NT; nt++)
                    acc[mt][nt] = __builtin_amdgcn_mfma_f32_16x16x32_bf16(
                        af[mt], bfr[nt], acc[mt][nt], 0, 0, 0);
        }
        __syncthreads();
    }

#pragma unroll
    for (int mt = 0; mt < MT; mt++)
#pragma unroll
        for (int nt = 0; nt < NT; nt++) {
            const int gn = bn0 + wn0 + nt * 16 + frow;
            const float bv = (float)bias[gn];
#pragma unroll
            for (int r = 0; r < 4; r++) {
                const int gm = bm0 + wm0 + mt * 16 + fquad * 4 + r;
                C[(size_t)gm * N + gn] = (bf16)gelu_exact(acc[mt][nt][r] + bv);
            }
        }
}

// ---------------------------------------------------------------------------
// MoE w2, both slots (disjoint outputs moe0/moe1). grid (142, 4).
// ---------------------------------------------------------------------------
__global__ __launch_bounds__(256) void gemm_moe_w2(
    const bf16* __restrict__ hid0, const bf16* __restrict__ hid1,
    const bf16* __restrict__ Wb, const bf16* __restrict__ biasb,
    bf16* __restrict__ moe0, bf16* __restrict__ moe1,
    const int* __restrict__ list, const float* __restrict__ lw,
    const int* __restrict__ tile_ex, const int* __restrict__ ntiles) {
    constexpr int BM = 128, BN = 64, BK = 64, WM = 32;
    constexpr int N = 256, K = 1024;
    const int slot = (blockIdx.x >= 71) ? 1 : 0;
    const int xi = blockIdx.x - slot * 71;
    if (xi >= ntiles[slot]) return;
    __shared__ alignas(16) bf16 As[BM * BK];
    __shared__ alignas(16) bf16 Ws[BN * BK];
    const bf16* A = slot ? hid1 : hid0;
    bf16* C = slot ? moe1 : moe0;
    const int* mylist = list + slot * 9216;
    const float* mylw = lw + slot * 9216;
    const int e = tile_ex[slot * 72 + xi];
    const bf16* W = Wb + (size_t)e * N * K;
    const bf16* bias = biasb + e * N;
    const int bm0 = xi * BM, bn0 = blockIdx.y * BN;
    const int tid = threadIdx.x;
    const int wave = tid >> 6, lane = tid & 63;
    const int wm0 = wave * WM;
    constexpr int MT = WM / 16, NT = 4;
    f32x4 acc[MT][NT] = {};
    const int frow = lane & 15, fquad = lane >> 4;

    const bf16* ag[4];
    const bf16* bg[2];
    unsigned al[4], bl[2];
#pragma unroll
    for (int i = 0; i < 4; i++) {
        const int d = wave * 256 + i * 64 + lane;
        const int r = d >> 3, c = ((d & 7) ^ (r & 7)) * 8;
        ag[i] = A + (size_t)(bm0 + r) * K + c;
        al[i] = (unsigned)(wave * 256 + i * 64) * 8u;
    }
#pragma unroll
    for (int i = 0; i < 2; i++) {
        const int d = wave * 128 + i * 64 + lane;
        const int r = d >> 3, c = ((d & 7) ^ (r & 7)) * 8;
        bg[i] = W + (size_t)(bn0 + r) * K + c;
        bl[i] = (unsigned)(wave * 128 + i * 64) * 8u;
    }

    for (int k0 = 0; k0 < K; k0 += BK) {
#pragma unroll
        for (int i = 0; i < 4; i++) GLOAD_LDS(ag[i] + k0, &As[al[i]]);
#pragma unroll
        for (int i = 0; i < 2; i++) GLOAD_LDS(bg[i] + k0, &Ws[bl[i]]);
        __syncthreads();
#pragma unroll
        for (int ks = 0; ks < 2; ks++) {
            bf16x8 af[MT], bfr[NT];
#pragma unroll
            for (int mt = 0; mt < MT; mt++)
                af[mt] = *(const bf16x8*)&As[SWZ(wm0 + mt * 16 + frow, ks * 4 + fquad)];
#pragma unroll
            for (int nt = 0; nt < NT; nt++)
                bfr[nt] = *(const bf16x8*)&Ws[SWZ(nt * 16 + frow, ks * 4 + fquad)];
#pragma unroll
            for (int mt = 0; mt < MT; mt++)
#pragma unroll
                for (int nt = 0; nt < NT; nt++)
                    acc[mt][nt] = __builtin_amdgcn_mfma_f32_16x16x32_bf16(
                        af[mt], bfr[nt], acc[mt][nt], 0, 0, 0);
        }
        __syncthreads();
    }

#pragma unroll
    for (int mt = 0; mt < MT; mt++)
#pragma unroll
        for (int nt = 0; nt < NT; nt++) {
            const int gn = bn0 + nt * 16 + frow;
            const float bv = (float)bias[gn];
#pragma unroll
            for (int r = 0; r < 4; r++) {
                const int gm = bm0 + wm0 + mt * 16 + fquad * 4 + r;
                const float v = acc[mt][nt][r] + bv;
                C[(size_t)mylist[gm] * 256 + gn] = (bf16)(mylw[gm] * v);
            }
        }
}

// ---------------------------------------------------------------------------
// Input projection + positional encoding. grid 8192, block 256.
// ---------------------------------------------------------------------------
__global__ __launch_bounds__(256) void input_proj_kernel(
    const bf16* __restrict__ x, const bf16* __restrict__ w,
    const bf16* __restrict__ b, bf16* __restrict__ h) {
    const int m = blockIdx.x, t = threadIdx.x;
    __shared__ float xs[46];
    if (t < 46) xs[t] = (float)x[m * 46 + t];
    __syncthreads();
    float acc = (float)b[t];
#pragma unroll
    for (int k = 0; k < 46; k++) acc += xs[k] * (float)w[t * 46 + k];
    const int s = m & 511;
    const int i = t >> 1;
    const float dv = expf((float)(2 * i) * (-9.210340371976184f / 256.0f));
    const float ang = (float)s * dv;
    const float pe = (t & 1) ? cosf(ang) : sinf(ang);
    h[(size_t)m * 256 + t] = (bf16)(acc + pe);
}

// ---------------------------------------------------------------------------
// Wave-per-token LayerNorm (ln2): h = LN(h + a0 + a1)*s + b. grid 2048.
// ---------------------------------------------------------------------------
__global__ __launch_bounds__(256) void ln_kernel(
    bf16* __restrict__ h, const bf16* __restrict__ a0,
    const bf16* __restrict__ a1, const bf16* __restrict__ s,
    const bf16* __restrict__ b) {
    const int m = blockIdx.x * 4 + (threadIdx.x >> 6);
    const int lane = threadIdx.x & 63;
    const int c0 = lane * 4;
    bf16x4 hv = *(const bf16x4*)&h[(size_t)m * 256 + c0];
    bf16x4 av = *(const bf16x4*)&a0[(size_t)m * 256 + c0];
    bf16x4 bv2 = *(const bf16x4*)&a1[(size_t)m * 256 + c0];
    float x[4];
    float s1 = 0.0f, s2 = 0.0f;
#pragma unroll
    for (int j = 0; j < 4; j++) {
        x[j] = (float)hv[j] + (float)av[j] + (float)bv2[j];
        s1 += x[j];
        s2 += x[j] * x[j];
    }
#pragma unroll
    for (int msk = 1; msk < 64; msk <<= 1) {
        s1 += __shfl_xor(s1, msk, 64);
        s2 += __shfl_xor(s2, msk, 64);
    }
    const float mean = s1 * (1.0f / 256.0f);
    const float var = fmaxf(s2 * (1.0f / 256.0f) - mean * mean, 0.0f);
    const float inv = rsqrtf(var + 1e-5f);
    bf16x4 sv = *(const bf16x4*)&s[c0];
    bf16x4 bv = *(const bf16x4*)&b[c0];
    bf16x4 o;
#pragma unroll
    for (int j = 0; j < 4; j++)
        o[j] = (bf16)((x[j] - mean) * inv * (float)sv[j] + (float)bv[j]);
    *(bf16x4*)&h[(size_t)m * 256 + c0] = o;
}

// ---------------------------------------------------------------------------
// Fused attention, one (b,h) x 32-query tile per block. grid (16,128).
// ---------------------------------------------------------------------------
__global__ __launch_bounds__(256) void attn_kernel(
    const bf16* __restrict__ qkv, const bf16* __restrict__ vT,
    bf16* __restrict__ aout) {
    __shared__ alignas(16) bf16 P[32][520];
    __shared__ float wsum[4][32];
    __shared__ float sinv[32];
    const int s0 = blockIdx.x * 32;
    const int b = blockIdx.y >> 3, hh = blockIdx.y & 7;
    const int tid = threadIdx.x, wave = tid >> 6, lane = tid & 63;
    const int frow = lane & 15, fquad = lane >> 4;
    const size_t base = (size_t)b * 512;
    const float CST = 0.25505654f;  // (1/sqrt(32)) * log2(e)

    bf16x8 qf[2];
#pragma unroll
    for (int mt = 0; mt < 2; mt++)
        qf[mt] = *(const bf16x8*)&qkv[(base + s0 + mt * 16 + frow) * 768 + hh * 32 + fquad * 8];
    float rsum[2][4] = {};
#pragma unroll
    for (int k8 = 0; k8 < 8; k8++) {
        const int key0 = (wave * 8 + k8) * 16;
        bf16x8 kf = *(const bf16x8*)&qkv[(base + key0 + frow) * 768 + 256 + hh * 32 + fquad * 8];
#pragma unroll
        for (int mt = 0; mt < 2; mt++) {
            f32x4 c = {};
            c = __builtin_amdgcn_mfma_f32_16x16x32_bf16(qf[mt], kf, c, 0, 0, 0);
#pragma unroll
            for (int r = 0; r < 4; r++) {
                const float e_ = __builtin_exp2f(fminf(c[r] * CST, 60.0f));
                P[mt * 16 + fquad * 4 + r][key0 + frow] = (bf16)e_;
                rsum[mt][r] += e_;
            }
        }
    }
#pragma unroll
    for (int mt = 0; mt < 2; mt++)
#pragma unroll
        for (int r = 0; r < 4; r++) {
#pragma unroll
            for (int m = 1; m < 16; m <<= 1)
                rsum[mt][r] += __shfl_xor(rsum[mt][r], m, 64);
        }
    if (frow == 0) {
#pragma unroll
        for (int mt = 0; mt < 2; mt++)
#pragma unroll
            for (int r = 0; r < 4; r++)
                wsum[wave][mt * 16 + fquad * 4 + r] = rsum[mt][r];
    }
    __syncthreads();
    if (tid < 32)
        sinv[tid] = 1.0f / (wsum[0][tid] + wsum[1][tid] + wsum[2][tid] + wsum[3][tid]);

    {
        const int mt = wave >> 1, nt = wave & 1;
        const bf16* vrow = &vT[((size_t)(b * 8 + hh) * 32 + nt * 16 + frow) * 512];
        f32x4 o = {};
#pragma unroll
        for (int ks = 0; ks < 16; ks++) {
            bf16x8 pf = *(const bf16x8*)&P[mt * 16 + frow][ks * 32 + fquad * 8];
            bf16x8 vf = *(const bf16x8*)&vrow[ks * 32 + fquad * 8];
            o = __builtin_amdgcn_mfma_f32_16x16x32_bf16(pf, vf, o, 0, 0, 0);
        }
        __syncthreads();
        const int r0 = mt * 16 + fquad * 4;
#pragma unroll
        for (int r = 0; r < 4; r++)
            aout[(base + s0 + r0 + r) * 256 + hh * 32 + nt * 16 + frow] =
                (bf16)(o[r] * sinv[r0 + r]);
    }
}

// ---------------------------------------------------------------------------
// Pooled attention + projection + heads.
// ---------------------------------------------------------------------------
__global__ __launch_bounds__(256) void pooled_attn_kernel(
    const bf16* __restrict__ qkv, const bf16* __restrict__ vT,
    bf16* __restrict__ pa) {
    const int wid = blockIdx.x * 4 + (threadIdx.x >> 6);
    const int lane = threadIdx.x & 63;
    const int b = wid >> 3, hh = wid & 7;
    const size_t base = (size_t)b * 512;
    const float scale = 0.17677669529663687f;
    float q[32];
#pragma unroll
    for (int d = 0; d < 32; d++) q[d] = (float)qkv[(base + 511) * 768 + hh * 32 + d];
    float sc[8];
    float mx = -1e30f;
#pragma unroll
    for (int j = 0; j < 8; j++) {
        const int key = lane + j * 64;
        const bf16* kr = &qkv[(base + key) * 768 + 256 + hh * 32];
        float s = 0.0f;
#pragma unroll
        for (int d = 0; d < 32; d++) s += q[d] * (float)kr[d];
        s *= scale;
        sc[j] = s;
        mx = fmaxf(mx, s);
    }
#pragma unroll
    for (int m = 1; m < 64; m <<= 1) mx = fmaxf(mx, __shfl_xor(mx, m, 64));
    float se = 0.0f;
#pragma unroll
    for (int j = 0; j < 8; j++) { sc[j] = expf(sc[j] - mx); se += sc[j]; }
#pragma unroll
    for (int m = 1; m < 64; m <<= 1) se += __shfl_xor(se, m, 64);
    float o[32] = {};
    const bf16* vb = &vT[(size_t)(b * 8 + hh) * 32 * 512];
#pragma unroll
    for (int d = 0; d < 32; d++) {
        const bf16* vr = vb + (size_t)d * 512;
#pragma unroll
        for (int j = 0; j < 8; j++)
            o[d] += sc[j] * (float)vr[lane + j * 64];
    }
#pragma unroll
    for (int d = 0; d < 32; d++) {
#pragma unroll
        for (int m = 1; m < 64; m <<= 1) o[d] += __shfl_xor(o[d], m, 64);
    }
    if (lane == 0) {
        const float inv = 1.0f / se;
        for (int d = 0; d < 32; d++) pa[b * 256 + hh * 32 + d] = (bf16)(o[d] * inv);
    }
}

__global__ __launch_bounds__(256) void pooled_proj_kernel(
    const bf16* __restrict__ pa, const bf16* __restrict__ w,
    const bf16* __restrict__ bias, bf16* __restrict__ pooled) {
    const int b = blockIdx.x, t = threadIdx.x;
    __shared__ float xs[256];
    xs[t] = (float)pa[b * 256 + t];
    __syncthreads();
    float acc = (float)bias[t];
    for (int k = 0; k < 256; k++) acc += xs[k] * (float)w[t * 256 + k];
    pooled[b * 256 + t] = (bf16)acc;
}

__global__ __launch_bounds__(256) void heads_kernel(
    const bf16* __restrict__ pooled,
    const bf16* __restrict__ aw1, const bf16* __restrict__ ab1,
    const bf16* __restrict__ aln1s, const bf16* __restrict__ aln1b,
    const bf16* __restrict__ aw2, const bf16* __restrict__ ab2,
    const bf16* __restrict__ aln2s, const bf16* __restrict__ aln2b,
    const bf16* __restrict__ aw3, const bf16* __restrict__ ab3,
    const bf16* __restrict__ pw1, const bf16* __restrict__ pb1,
    const bf16* __restrict__ pln1s, const bf16* __restrict__ pln1b,
    const bf16* __restrict__ pw2, const bf16* __restrict__ pb2,
    const bf16* __restrict__ pln2s, const bf16* __restrict__ pln2b,
    const bf16* __restrict__ pw3, const bf16* __restrict__ pb3,
    float* __restrict__ out) {
    const int b = blockIdx.x, t = threadIdx.x;
    __shared__ float pool[256], buf[256], buf2[256], r1[256], r2[256];
    pool[t] = (float)pooled[b * 256 + t];
    __syncthreads();

    auto block_ln = [&](float* v, int W, const bf16* ls, const bf16* lb) {
        const float val = (t < W) ? v[t] : 0.0f;
        r1[t] = val;
        r2[t] = val * val;
        __syncthreads();
        for (int off = 128; off > 0; off >>= 1) {
            if (t < off) { r1[t] += r1[t + off]; r2[t] += r2[t + off]; }
            __syncthreads();
        }
        const float mean = r1[0] / (float)W;
        const float var = fmaxf(r2[0] / (float)W - mean * mean, 0.0f);
        const float inv = rsqrtf(var + 1e-5f);
        __syncthreads();
        if (t < W) v[t] = (val - mean) * inv * (float)ls[t] + (float)lb[t];
        __syncthreads();
    };

    float a;
    if (t < 128) {
        a = (float)ab1[t];
        for (int k = 0; k < 256; k++) a += pool[k] * (float)aw1[t * 256 + k];
        buf[t] = gelu_exact(a);
    }
    __syncthreads();
    block_ln(buf, 128, aln1s, aln1b);
    if (t < 64) {
        a = (float)ab2[t];
        for (int k = 0; k < 128; k++) a += buf[k] * (float)aw2[t * 128 + k];
        buf2[t] = gelu_exact(a);
    }
    __syncthreads();
    block_ln(buf2, 64, aln2s, aln2b);
    if (t < 3) {
        a = (float)ab3[t];
        for (int k = 0; k < 64; k++) a += buf2[k] * (float)aw3[t * 64 + k];
        out[b * 3 + t] = a;
    }

    a = (float)pb1[t];
    for (int k = 0; k < 256; k++) a += pool[k] * (float)pw1[t * 256 + k];
    buf[t] = a;
    __syncthreads();
    block_ln(buf, 256, pln1s, pln1b);
    buf[t] = gelu_exact(buf[t]);
    __syncthreads();
    if (t < 128) {
        a = (float)pb2[t];
        for (int k = 0; k < 256; k++) a += buf[k] * (float)pw2[t * 256 + k];
        buf2[t] = a;
    }
    __syncthreads();
    block_ln(buf2, 128, pln2s, pln2b);
    if (t < 128) buf2[t] = gelu_exact(buf2[t]);
    __syncthreads();
    if (t == 0) {
        a = (float)pb3[0];
        for (int k = 0; k < 128; k++) a += buf2[k] * (float)pw3[k];
        out[48 + b] = a;
    }
}

__global__ void aux_kernel(const float* __restrict__ sums, float* __restrict__ out) {
    if (threadIdx.x == 0 && blockIdx.x == 0) {
        float tot = 0.0f;
        for (int l = 0; l < 6; l++)
            for (int e = 0; e < 8; e++) {
                const float mn = sums[l * 8 + e] * (1.0f / 8192.0f);
                tot += 8.0f * mn * mn;
            }
        out[64] = tot;
    }
}

// ---------------------------------------------------------------------------
extern "C" void kernel_launch(void* const* d_in, const int* in_sizes, int n_in,
                              void* d_out, int out_size, void* d_ws, size_t ws_size,
                              hipStream_t stream) {
    char* ws = (char*)d_ws;
    const size_t MB = 1024 * 1024;
    bf16*  h     = (bf16*)(ws);                        // 8193x256
    bf16*  moe0  = (bf16*)(ws + 8 * MB);
    bf16*  moe1  = (bf16*)(ws + 13 * MB);
    char*  ctrl  = ws + 20 * MB;
    float* auxs    = (float*)(ctrl + 0);               // 48 f32
    int*   flag    = (int*)(ctrl + 192);
    int*   ntiles  = (int*)(ctrl + 256);               // [2]
    int*   tileex  = (int*)(ctrl + 320);               // [2][72]
    float* ostage  = (float*)(ctrl + 1024);            // 65 f32
    int*   g_hist  = (int*)(ctrl + 2048);              // [256][16]
    float* auxpart = (float*)(ctrl + 18432);           // [256][8]
    int*   top_e   = (int*)(ctrl + 26624);             // [2][8192]
    float* top_w   = (float*)(ctrl + 92160);           // [2][8192]
    int*   list    = (int*)(ctrl + 157696);            // [2][9216]
    float* lw      = (float*)(ctrl + 231424);          // [2][9216]
    bf16*  qkv   = (bf16*)(ws + 24 * MB);              // 8192x768
    bf16*  aoutb = (bf16*)(ws + 40 * MB);              // 8192x256
    bf16*  hid0  = (bf16*)(ws + 56 * MB);              // 9216x1024
    bf16*  hid1  = (bf16*)(ws + 80 * MB);              // 9216x1024
    bf16*  vT    = (bf16*)(ws + 104 * MB);             // [16][8][32][512]
    bf16*  pattn  = (bf16*)(ws + 110 * MB);
    bf16*  pooled = (bf16*)(ws + 110 * MB + 8192);
    bf16*  cvbase = (bf16*)(ws + 112 * MB);            // ~10.6 MB

    InTab tab;
    unsigned off = 0;
    bf16* cv[NIN];
    for (int i = 0; i < NIN; i++) {
        tab.src[i] = d_in[i];
        tab.off[i] = off;
        tab.n[i] = (unsigned)in_sizes[i];
        cv[i] = cvbase + off;
        off += ((unsigned)in_sizes[i] + 1023u) & ~1023u;
    }
    const int cv_blocks = (int)(off >> 10);

    const bf16 *x = cv[0], *in_w = cv[1], *in_b = cv[2], *qkv_w = cv[3], *qkv_b = cv[4],
               *out_w = cv[5], *out_b = cv[6], *gate_w = cv[7], *gate_b = cv[8],
               *e_w1 = cv[9], *e_b1 = cv[10], *e_w2 = cv[11], *e_b2 = cv[12],
               *ln1_s = cv[13], *ln1_b = cv[14], *ln2_s = cv[15], *ln2_b = cv[16],
               *pqkv_w = cv[17], *pqkv_b = cv[18], *pout_w = cv[19], *pout_b = cv[20],
               *a_w1 = cv[21], *a_b1 = cv[22], *a_ln1s = cv[23], *a_ln1b = cv[24],
               *a_w2 = cv[25], *a_b2 = cv[26], *a_ln2s = cv[27], *a_ln2b = cv[28],
               *a_w3 = cv[29], *a_b3 = cv[30],
               *pr_w1 = cv[31], *pr_b1 = cv[32], *pr_ln1s = cv[33], *pr_ln1b = cv[34],
               *pr_w2 = cv[35], *pr_b2 = cv[36], *pr_ln2s = cv[37], *pr_ln2b = cv[38],
               *pr_w3 = cv[39], *pr_b3 = cv[40];

    sniff_kernel<<<1, 256, 0, stream>>>((const unsigned*)d_in[0], flag);
    convert_kernel<<<cv_blocks, 256, 0, stream>>>(tab, cvbase, flag);

    hipMemsetAsync(auxs, 0, 192, stream);
    input_proj_kernel<<<8192, 256, 0, stream>>>(x, in_w, in_b, h);

    for (int l = 0; l < 6; l++) {
        gemm_bt<64, 128, 32, 64, true><<<dim3(128, 6), 256, 0, stream>>>(
            h, qkv_w, qkv_b, qkv, 8192, 768, 256, vT);
        attn_kernel<<<dim3(16, 128), 256, 0, stream>>>(qkv, vT, aoutb);
        outproj_gate_kernel<<<256, 256, 0, stream>>>(
            aoutb, out_w, out_b, h, ln1_s, ln1_b, gate_w, gate_b,
            top_e, top_w, g_hist, auxpart);
        scatter_route_kernel<<<256, 256, 0, stream>>>(
            g_hist, auxpart, top_e, top_w, ntiles, tileex, list, lw, auxs + l * 8);
        gemm_moe_w1<<<dim3(142, 8), 256, 0, stream>>>(
            h, e_w1, e_b1, hid0, hid1, list, tileex, ntiles);
        gemm_moe_w2<<<dim3(142, 4), 256, 0, stream>>>(
            hid0, hid1, e_w2, e_b2, moe0, moe1, list, lw, tileex, ntiles);
        ln_kernel<<<2048, 256, 0, stream>>>(h, moe0, moe1, ln2_s, ln2_b);
    }

    gemm_bt<64, 128, 32, 64, true><<<dim3(128, 6), 256, 0, stream>>>(
        h, pqkv_w, pqkv_b, qkv, 8192, 768, 256, vT);
    pooled_attn_kernel<<<32, 256, 0, stream>>>(qkv, vT, pattn);
    pooled_proj_kernel<<<16, 256, 0, stream>>>(pattn, pout_w, pout_b, pooled);

    heads_kernel<<<16, 256, 0, stream>>>(
        pooled,
        a_w1, a_b1, a_ln1s, a_ln1b, a_w2, a_b2, a_ln2s, a_ln2b, a_w3, a_b3,
        pr_w1, pr_b1, pr_ln1s, pr_ln1b, pr_w2, pr_b2, pr_ln2s, pr_ln2b, pr_w3, pr_b3,
        ostage);
    aux_kernel<<<1, 64, 0, stream>>>(auxs, ostage);
    out_convert_kernel<<<1, 128, 0, stream>>>(ostage, d_out, flag);
}